// Round 14
// baseline (533.962 us; speedup 1.0000x reference)
//
#include <hip/hip_runtime.h>
#include <hip/hip_bf16.h>
#include <stdint.h>

#define TOKENS 2048
#define HDIM 1024
#define FDIM 3584
#define NEXP 8
#define BK 32

typedef __attribute__((ext_vector_type(8))) short short8;
typedef __attribute__((ext_vector_type(4))) float floatx4;

#define AS1 __attribute__((address_space(1)))
#define AS3 __attribute__((address_space(3)))

__device__ __forceinline__ void glds16(const void* g, void* l) {
  __builtin_amdgcn_global_load_lds((const AS1 void*)g, (AS3 void*)l, 16, 0, 0);
}

// Raw barrier with COUNTED vmcnt: retires the A glds16 (oldest) but leaves the
// 4 B-prefetch loads in flight across the barrier. lgkmcnt(0) publishes this
// step's ds_writes. sched_barrier fences per guide rule #18.
// gemm1: in-flight = 4 glds + 4 B = 8 -> vmcnt(4) waits exactly the glds.
// gemm2: in-flight = 2 glds + 4 B = 6 -> vmcnt(4) waits exactly the glds.
#define PIPE_BARRIER() do {                                        \
  asm volatile("s_waitcnt vmcnt(4) lgkmcnt(0)" ::: "memory");      \
  __builtin_amdgcn_sched_barrier(0);                               \
  __builtin_amdgcn_s_barrier();                                    \
  __builtin_amdgcn_sched_barrier(0);                               \
} while (0)

__device__ __forceinline__ unsigned short f2bf(float f) {
  union { float f; unsigned int u; } c; c.f = f;
  unsigned int u = c.u;
  u += 0x7fffu + ((u >> 16) & 1u);
  return (unsigned short)(u >> 16);
}

__device__ __forceinline__ unsigned int pk2bf(float a, float b) {
  __hip_bfloat162 h = __float22bfloat162_rn(make_float2(a, b));
  union { __hip_bfloat162 h; unsigned int u; } c; c.h = h;
  return c.u;
}

__device__ __forceinline__ short8 pack_bf16(float4 c0, float4 c1) {
  union { short8 s; uint4 u; } o;
  o.u.x = pk2bf(c0.x, c0.y); o.u.y = pk2bf(c0.z, c0.w);
  o.u.z = pk2bf(c1.x, c1.y); o.u.w = pk2bf(c1.z, c1.w);
  return o.s;
}

// ---------------- gating + x->bf16 conversion fused (vectorized) ----------------
__global__ void gate_kernel(const float* __restrict__ x,
                            const float* __restrict__ gw,
                            unsigned short* __restrict__ xbf,
                            int* __restrict__ top_e,
                            float* __restrict__ top_w) {
  int wv = threadIdx.x >> 6;
  int lane = threadIdx.x & 63;
  int t = blockIdx.x * 4 + wv;
  if (t >= TOKENS) return;
  float p[NEXP];
#pragma unroll
  for (int e = 0; e < NEXP; e++) p[e] = 0.f;
  const float* xr = x + (size_t)t * HDIM;
  unsigned short* xb = xbf + (size_t)t * HDIM;
#pragma unroll
  for (int it = 0; it < 4; it++) {
    int h = it * 256 + lane * 4;
    float4 v = *(const float4*)(xr + h);
    uint2 pk;
    pk.x = pk2bf(v.x, v.y);
    pk.y = pk2bf(v.z, v.w);
    *(uint2*)(xb + h) = pk;
    const float* g0 = gw + (size_t)h * NEXP;
#pragma unroll
    for (int j = 0; j < 4; j++) {
      float xv = (j == 0) ? v.x : (j == 1) ? v.y : (j == 2) ? v.z : v.w;
      const float4* g4 = (const float4*)(g0 + j * NEXP);
      float4 a = g4[0], b = g4[1];
      p[0] += xv * a.x; p[1] += xv * a.y; p[2] += xv * a.z; p[3] += xv * a.w;
      p[4] += xv * b.x; p[5] += xv * b.y; p[6] += xv * b.z; p[7] += xv * b.w;
    }
  }
#pragma unroll
  for (int e = 0; e < NEXP; e++) {
#pragma unroll
    for (int off = 32; off > 0; off >>= 1) p[e] += __shfl_xor(p[e], off, 64);
  }
  if (lane == 0) {
    int i0 = 0;
    for (int e = 1; e < NEXP; e++) if (p[e] > p[i0]) i0 = e;
    int i1 = (i0 == 0) ? 1 : 0;
    for (int e = 0; e < NEXP; e++) if (e != i0 && p[e] > p[i1]) i1 = e;
    float l0 = p[i0], l1 = p[i1];
    float e1 = __expf(l1 - l0);
    float s = 1.f + e1;
    top_e[t * 2] = i0; top_e[t * 2 + 1] = i1;
    top_w[t * 2] = 1.f / s; top_w[t * 2 + 1] = e1 / s;
  }
}

// ---------------- fused count + offsets + scatter (single block, LDS atomics only) ----------------
__global__ void route_kernel(const int* __restrict__ top_e,
                             int* __restrict__ count,
                             int* __restrict__ offs,
                             int* __restrict__ tok_of,
                             int* __restrict__ slot_of) {
  __shared__ int hist[NEXP];
  __shared__ int cur[NEXP];
  int tid = threadIdx.x;  // 1024 threads, 4 entries each
  if (tid < NEXP) hist[tid] = 0;
  __syncthreads();
  int e[4];
#pragma unroll
  for (int j = 0; j < 4; j++) {
    int i = tid * 4 + j;
    e[j] = top_e[i];
    atomicAdd(&hist[e[j]], 1);
  }
  __syncthreads();
  if (tid == 0) {
    int o = 0;
    for (int k = 0; k < NEXP; k++) {
      offs[k] = o; cur[k] = o; count[k] = hist[k]; o += hist[k];
    }
  }
  __syncthreads();
#pragma unroll
  for (int j = 0; j < 4; j++) {
    int i = tid * 4 + j;
    int g = atomicAdd(&cur[e[j]], 1);
    tok_of[g] = i >> 1;
    slot_of[i] = g;
  }
}

// ---------------- GEMM1: act = silu(X w1^T) * (X w3^T), 256x64 tile ----------------
// 256-row M-tile: 32 MFMA per K-step per wave (2x the work per barrier to
// amortize the lockstep serialization measured at ~5000 cyc/step with only
// 16 MFMA). A (bf16 x): 4x glds16/thread. B (fp32 w1/w3): distance-2 register
// pipeline + counted-vmcnt barrier (B loads cross the barrier).
#define G1_BM 256
#define G1_BF 64

__global__ __launch_bounds__(256, 3)
void gemm1_kernel(const unsigned short* __restrict__ xbf,
                  const float* __restrict__ w1,
                  const float* __restrict__ w3,
                  const int* __restrict__ count,
                  const int* __restrict__ offs,
                  const int* __restrict__ tok_of,
                  unsigned short* __restrict__ act) {
  int e = blockIdx.z;
  int cnt = count[e];
  int m0 = blockIdx.y * G1_BM;
  if (m0 >= cnt) return;
  int f0 = blockIdx.x * G1_BF;
  int off_e = offs[e];

  __shared__ __align__(16) unsigned short sA[2 * G1_BM * 32];   // 2 x 16 KB
  __shared__ __align__(16) unsigned short sB1[2 * G1_BF * 32];  // 2 x 4 KB
  __shared__ __align__(16) unsigned short sB3[2 * G1_BF * 32];  // 2 x 4 KB

  int tid = threadIdx.x;
  int lane = tid & 63, wv = tid >> 6;

  // A staging: 1024 chunks -> 4 per thread (glds16, wave-uniform LDS base)
  const unsigned short* ag[4];
  char* alb[4];
#pragma unroll
  for (int p = 0; p < 4; p++) {
    int c = tid + p * 256;
    int row = c >> 2, slot = c & 3;
    int gch = slot ^ ((row >> 1) & 3);
    int r = m0 + row;
    int tok = tok_of[off_e + (r < cnt ? r : 0)];
    ag[p] = xbf + (size_t)tok * HDIM + gch * 8;
    alb[p] = (char*)sA + (wv * 64 + p * 256) * 16;
  }
  // B staging: 256 chunks each, 1 per thread: read 8 fp32, write 8 bf16 (16B)
  const float *b1g, *b3g;
  unsigned short *b1l, *b3l;
  {
    int row = tid >> 2, slot = tid & 3;
    int gch = slot ^ ((row >> 1) & 3);
    size_t wrow = (size_t)e * FDIM + f0 + row;
    b1g = w1 + wrow * HDIM + gch * 8;
    b3g = w3 + wrow * HDIM + gch * 8;
    b1l = sB1 + tid * 8;
    b3l = sB3 + tid * 8;
  }

  int lrow = lane & 15, quad = lane >> 4;
  int wm = wv >> 1, wn = wv & 1;

  floatx4 acc1[8][2], acc3[8][2];
#pragma unroll
  for (int i = 0; i < 8; i++)
#pragma unroll
    for (int j = 0; j < 2; j++) {
      acc1[i][j] = (floatx4){0.f, 0.f, 0.f, 0.f};
      acc3[i][j] = (floatx4){0.f, 0.f, 0.f, 0.f};
    }

  const int NT = HDIM / BK;  // 32

  // prologue: stage tile 0 into buf 0 + preload B(1) into regs
#pragma unroll
  for (int p = 0; p < 4; p++) glds16(ag[p], alb[p]);
  asm volatile("" ::: "memory");   // glds stay older than the loads below
  {
    float4 a0 = *(const float4*)(b1g), a1 = *(const float4*)(b1g + 4);
    float4 c0 = *(const float4*)(b3g), c1 = *(const float4*)(b3g + 4);
    *(short8*)b1l = pack_bf16(a0, a1);
    *(short8*)b3l = pack_bf16(c0, c1);
  }
  float4 cu0 = *(const float4*)(b1g + BK), cu1 = *(const float4*)(b1g + BK + 4);
  float4 cv0 = *(const float4*)(b3g + BK), cv1 = *(const float4*)(b3g + BK + 4);
  PIPE_BARRIER();

  int cur = 0;
  for (int t = 0; t < NT; t++) {
    int nb = cur ^ 1;
    // B(t+1): regs aged one full step + barrier; compiler waits their vmcnt.
    *(short8*)(b1l + nb * (G1_BF * 32)) = pack_bf16(cu0, cu1);
    *(short8*)(b3l + nb * (G1_BF * 32)) = pack_bf16(cv0, cv1);
    // A(t+1) glds issued FIRST -> they are the ops vmcnt(4) waits for.
    int k1 = (t + 1 < NT) ? (t + 1) * BK : 0;
#pragma unroll
    for (int p = 0; p < 4; p++) glds16(ag[p] + k1, alb[p] + nb * 16384);
    asm volatile("" ::: "memory");
    // B(t+2) prefetch: stays in flight across the barrier.
    int k2 = (t + 2 < NT) ? (t + 2) * BK : 0;
    float4 nu0 = *(const float4*)(b1g + k2);
    float4 nu1 = *(const float4*)(b1g + k2 + 4);
    float4 nv0 = *(const float4*)(b3g + k2);
    float4 nv1 = *(const float4*)(b3g + k2 + 4);

    const unsigned short* sAc = sA + cur * (G1_BM * 32);
    const unsigned short* sB1c = sB1 + cur * (G1_BF * 32);
    const unsigned short* sB3c = sB3 + cur * (G1_BF * 32);

    short8 af[8], b1f[2], b3f[2];
#pragma unroll
    for (int ms = 0; ms < 8; ms++) {
      int r = wm * 128 + ms * 16 + lrow;
      int sl = quad ^ ((r >> 1) & 3);
      af[ms] = *(const short8*)(sAc + r * 32 + sl * 8);
    }
#pragma unroll
    for (int ns = 0; ns < 2; ns++) {
      int r = wn * 32 + ns * 16 + lrow;
      int sl = quad ^ ((r >> 1) & 3);
      b1f[ns] = *(const short8*)(sB1c + r * 32 + sl * 8);
      b3f[ns] = *(const short8*)(sB3c + r * 32 + sl * 8);
    }
#pragma unroll
    for (int ms = 0; ms < 8; ms++)
#pragma unroll
      for (int ns = 0; ns < 2; ns++) {
        acc1[ms][ns] = __builtin_amdgcn_mfma_f32_16x16x32_bf16(af[ms], b1f[ns], acc1[ms][ns], 0, 0, 0);
        acc3[ms][ns] = __builtin_amdgcn_mfma_f32_16x16x32_bf16(af[ms], b3f[ns], acc3[ms][ns], 0, 0, 0);
      }

    cu0 = nu0; cu1 = nu1; cv0 = nv0; cv1 = nv1;
    PIPE_BARRIER();
    cur = nb;
  }

#pragma unroll
  for (int ms = 0; ms < 8; ms++) {
#pragma unroll
    for (int reg = 0; reg < 4; reg++) {
      int slot = m0 + wm * 128 + ms * 16 + quad * 4 + reg;
      if (slot < cnt) {
        unsigned short* ar = act + (size_t)(off_e + slot) * FDIM + f0 + wn * 32;
#pragma unroll
        for (int ns = 0; ns < 2; ns++) {
          float h = acc1[ms][ns][reg];
          float g = acc3[ms][ns][reg];
          float a = h / (1.f + __expf(-h)) * g;
          ar[ns * 16 + lrow] = f2bf(a);
        }
      }
    }
  }
}

// ---------------- GEMM2: partial[sk] = act w2^T over K-slice, 128x128 tile ----------------
// A (bf16 act): glds16. B (fp32 w2): distance-2 pipeline, counted-vmcnt barrier.
// (BM=256 here would underfill the grid: only ~256 active blocks < 768 slots.)
#define G2_BM 128
#define G2_BN 128
#define SPLITK 2
#define G2_KS (FDIM / SPLITK)   // 1792

__global__ __launch_bounds__(256, 3)
void gemm2_kernel(const unsigned short* __restrict__ act,
                  const float* __restrict__ w2,
                  const int* __restrict__ count,
                  const int* __restrict__ offs,
                  float* __restrict__ part) {
  int zz = blockIdx.z;
  int e = zz & 7, sk = zz >> 3;
  int cnt = count[e];
  int m0 = blockIdx.y * G2_BM;
  if (m0 >= cnt) return;
  int h0 = blockIdx.x * G2_BN;
  int off_e = offs[e];
  int kb = sk * G2_KS;

  __shared__ __align__(16) unsigned short sA[2 * G2_BM * 32];  // 2 x 8 KB
  __shared__ __align__(16) unsigned short sB[2 * G2_BN * 32];  // 2 x 8 KB

  int tid = threadIdx.x;
  int lane = tid & 63, wv = tid >> 6;

  const unsigned short* ag[2];
  char* alb[2];
#pragma unroll
  for (int p = 0; p < 2; p++) {
    int c = tid + p * 256;
    int row = c >> 2, slot = c & 3;
    int gch = slot ^ ((row >> 1) & 3);
    int r = m0 + row;
    int rr = (r < cnt ? r : 0);
    ag[p] = act + (size_t)(off_e + rr) * FDIM + kb + gch * 8;
    alb[p] = (char*)sA + (wv * 64 + p * 256) * 16;
  }
  const float* bg[2];
  unsigned short* bl[2];
#pragma unroll
  for (int p = 0; p < 2; p++) {
    int c = tid + p * 256;
    int row = c >> 2, slot = c & 3;
    int gch = slot ^ ((row >> 1) & 3);
    bg[p] = w2 + ((size_t)e * HDIM + h0 + row) * FDIM + kb + gch * 8;
    bl[p] = sB + c * 8;
  }

  int lrow = lane & 15, quad = lane >> 4;
  int wm = wv >> 1, wn = wv & 1;

  floatx4 acc[4][4];
#pragma unroll
  for (int i = 0; i < 4; i++)
#pragma unroll
    for (int j = 0; j < 4; j++) acc[i][j] = (floatx4){0.f, 0.f, 0.f, 0.f};

  const int NT = G2_KS / BK;  // 56

  // prologue: stage tile 0 + preload B(1)
#pragma unroll
  for (int p = 0; p < 2; p++) glds16(ag[p], alb[p]);
  asm volatile("" ::: "memory");
#pragma unroll
  for (int p = 0; p < 2; p++) {
    float4 a0 = *(const float4*)(bg[p]);
    float4 a1 = *(const float4*)(bg[p] + 4);
    *(short8*)(bl[p]) = pack_bf16(a0, a1);
  }
  float4 cu0[2], cu1[2];
#pragma unroll
  for (int p = 0; p < 2; p++) {
    cu0[p] = *(const float4*)(bg[p] + BK);
    cu1[p] = *(const float4*)(bg[p] + BK + 4);
  }
  PIPE_BARRIER();

  int cur = 0;
  for (int t = 0; t < NT; t++) {
    int nb = cur ^ 1;
#pragma unroll
    for (int p = 0; p < 2; p++)
      *(short8*)(bl[p] + nb * (G2_BN * 32)) = pack_bf16(cu0[p], cu1[p]);
    int k1 = (t + 1 < NT) ? (t + 1) * BK : 0;
#pragma unroll
    for (int p = 0; p < 2; p++) glds16(ag[p] + k1, alb[p] + nb * 8192);
    asm volatile("" ::: "memory");
    int k2 = (t + 2 < NT) ? (t + 2) * BK : 0;
    float4 nu0[2], nu1[2];
#pragma unroll
    for (int p = 0; p < 2; p++) {
      nu0[p] = *(const float4*)(bg[p] + k2);
      nu1[p] = *(const float4*)(bg[p] + k2 + 4);
    }

    const unsigned short* sAc = sA + cur * (G2_BM * 32);
    const unsigned short* sBc = sB + cur * (G2_BN * 32);

    short8 af[4], bf[4];
#pragma unroll
    for (int ms = 0; ms < 4; ms++) {
      int r = wm * 64 + ms * 16 + lrow;
      int sl = quad ^ ((r >> 1) & 3);
      af[ms] = *(const short8*)(sAc + r * 32 + sl * 8);
    }
#pragma unroll
    for (int ns = 0; ns < 4; ns++) {
      int r = wn * 64 + ns * 16 + lrow;
      int sl = quad ^ ((r >> 1) & 3);
      bf[ns] = *(const short8*)(sBc + r * 32 + sl * 8);
    }
#pragma unroll
    for (int ms = 0; ms < 4; ms++)
#pragma unroll
      for (int ns = 0; ns < 4; ns++)
        acc[ms][ns] = __builtin_amdgcn_mfma_f32_16x16x32_bf16(af[ms], bf[ns], acc[ms][ns], 0, 0, 0);

#pragma unroll
    for (int p = 0; p < 2; p++) { cu0[p] = nu0[p]; cu1[p] = nu1[p]; }
    PIPE_BARRIER();
    cur = nb;
  }

#pragma unroll
  for (int ms = 0; ms < 4; ms++) {
#pragma unroll
    for (int reg = 0; reg < 4; reg++) {
      int slot = m0 + wm * 64 + ms * 16 + quad * 4 + reg;
      if (slot < cnt) {
        float* crow = part + ((size_t)sk * 4096 + off_e + slot) * HDIM + h0 + wn * 64;
#pragma unroll
        for (int ns = 0; ns < 4; ns++)
          crow[ns * 16 + lrow] = acc[ms][ns][reg];
      }
    }
  }
}

// ---------------- combine: out[t] = sum_k w_k * sum_sk part[sk][g_k] ----------------
__global__ void combine_kernel(const float* __restrict__ part,
                               const int* __restrict__ slot_of,
                               const float* __restrict__ top_w,
                               float* __restrict__ out) {
  int t = blockIdx.x;
  int g0 = slot_of[t * 2], g1 = slot_of[t * 2 + 1];
  float w0 = top_w[t * 2], w1 = top_w[t * 2 + 1];
  int i = threadIdx.x;   // 256 threads x float4 = 1024 floats
  float4 s0 = {0.f, 0.f, 0.f, 0.f}, s1 = {0.f, 0.f, 0.f, 0.f};
#pragma unroll
  for (int sk = 0; sk < SPLITK; sk++) {
    float4 a = ((const float4*)(part + ((size_t)sk * 4096 + g0) * HDIM))[i];
    float4 b = ((const float4*)(part + ((size_t)sk * 4096 + g1) * HDIM))[i];
    s0.x += a.x; s0.y += a.y; s0.z += a.z; s0.w += a.w;
    s1.x += b.x; s1.y += b.y; s1.z += b.z; s1.w += b.w;
  }
  float4 r;
  r.x = w0 * s0.x + w1 * s1.x;
  r.y = w0 * s0.y + w1 * s1.y;
  r.z = w0 * s0.z + w1 * s1.z;
  r.w = w0 * s0.w + w1 * s1.w;
  ((float4*)(out + (size_t)t * HDIM))[i] = r;
}

// ---------------- launcher ----------------
extern "C" void kernel_launch(void* const* d_in, const int* in_sizes, int n_in,
                              void* d_out, int out_size, void* d_ws, size_t ws_size,
                              hipStream_t stream) {
  const float* x  = (const float*)d_in[0];
  const float* gw = (const float*)d_in[1];
  const float* w1 = (const float*)d_in[2];
  const float* w3 = (const float*)d_in[3];
  const float* w2 = (const float*)d_in[4];
  float* out = (float*)d_out;

  char* ws = (char*)d_ws;
  const size_t MB = 1ull << 20;
  // layout (~67 MB total):
  //   [0,1)    small buffers
  //   [1,5)    xbf (4 MB)
  //   [5,35)   act  (28 MB used)
  //   [35,67)  part (32 MB, SPLITK=2)
  float* top_w = (float*)(ws);
  int* top_e   = (int*)(ws + 16384);
  int* slot_of = (int*)(ws + 32768);
  int* tok_of  = (int*)(ws + 49152);
  int* count   = (int*)(ws + 65536);
  int* offs    = (int*)(ws + 65536 + 64);

  unsigned short* xbf = (unsigned short*)(ws + 1 * MB);
  unsigned short* act = (unsigned short*)(ws + 5 * MB);
  float* part = (float*)(ws + 35 * MB);

  gate_kernel<<<TOKENS / 4, 256, 0, stream>>>(x, gw, xbf, top_e, top_w);
  route_kernel<<<1, 1024, 0, stream>>>(top_e, count, offs, tok_of, slot_of);
  gemm1_kernel<<<dim3(FDIM / G1_BF, TOKENS / G1_BM, NEXP), 256, 0, stream>>>(
      xbf, w1, w3, count, offs, tok_of, act);
  gemm2_kernel<<<dim3(HDIM / G2_BN, TOKENS / G2_BM, NEXP * SPLITK), 256, 0, stream>>>(
      act, w2, count, offs, part);
  combine_kernel<<<TOKENS, 256, 0, stream>>>(part, slot_of, top_w, out);
}

// Round 18
// 481.380 us; speedup vs baseline: 1.1092x; 1.1092x over previous
//
#include <hip/hip_runtime.h>
#include <hip/hip_bf16.h>
#include <stdint.h>

#define TOKENS 2048
#define HDIM 1024
#define FDIM 3584
#define NEXP 8
#define BK 32

typedef __attribute__((ext_vector_type(8))) short short8;
typedef __attribute__((ext_vector_type(4))) float floatx4;

#define AS1 __attribute__((address_space(1)))
#define AS3 __attribute__((address_space(3)))

__device__ __forceinline__ void glds16(const void* g, void* l) {
  __builtin_amdgcn_global_load_lds((const AS1 void*)g, (AS3 void*)l, 16, 0, 0);
}

// Raw barrier with COUNTED vmcnt: retires the 2 A-glds16 (oldest) but leaves
// the 4 B-prefetch loads in flight across the barrier. lgkmcnt(0) publishes
// this step's ds_writes. sched_barrier fences per guide rule #18.
// Both GEMMs: in-flight = 2 glds + 4 B = 6 -> vmcnt(4) waits exactly the glds.
#define PIPE_BARRIER() do {                                        \
  asm volatile("s_waitcnt vmcnt(4) lgkmcnt(0)" ::: "memory");      \
  __builtin_amdgcn_sched_barrier(0);                               \
  __builtin_amdgcn_s_barrier();                                    \
  __builtin_amdgcn_sched_barrier(0);                               \
} while (0)

__device__ __forceinline__ unsigned short f2bf(float f) {
  union { float f; unsigned int u; } c; c.f = f;
  unsigned int u = c.u;
  u += 0x7fffu + ((u >> 16) & 1u);
  return (unsigned short)(u >> 16);
}

__device__ __forceinline__ unsigned int pk2bf(float a, float b) {
  __hip_bfloat162 h = __float22bfloat162_rn(make_float2(a, b));
  union { __hip_bfloat162 h; unsigned int u; } c; c.h = h;
  return c.u;
}

__device__ __forceinline__ short8 pack_bf16(float4 c0, float4 c1) {
  union { short8 s; uint4 u; } o;
  o.u.x = pk2bf(c0.x, c0.y); o.u.y = pk2bf(c0.z, c0.w);
  o.u.z = pk2bf(c1.x, c1.y); o.u.w = pk2bf(c1.z, c1.w);
  return o.s;
}

// ---------------- gating + x->bf16 conversion fused (vectorized) ----------------
__global__ void gate_kernel(const float* __restrict__ x,
                            const float* __restrict__ gw,
                            unsigned short* __restrict__ xbf,
                            int* __restrict__ top_e,
                            float* __restrict__ top_w) {
  int wv = threadIdx.x >> 6;
  int lane = threadIdx.x & 63;
  int t = blockIdx.x * 4 + wv;
  if (t >= TOKENS) return;
  float p[NEXP];
#pragma unroll
  for (int e = 0; e < NEXP; e++) p[e] = 0.f;
  const float* xr = x + (size_t)t * HDIM;
  unsigned short* xb = xbf + (size_t)t * HDIM;
#pragma unroll
  for (int it = 0; it < 4; it++) {
    int h = it * 256 + lane * 4;
    float4 v = *(const float4*)(xr + h);
    uint2 pk;
    pk.x = pk2bf(v.x, v.y);
    pk.y = pk2bf(v.z, v.w);
    *(uint2*)(xb + h) = pk;
    const float* g0 = gw + (size_t)h * NEXP;
#pragma unroll
    for (int j = 0; j < 4; j++) {
      float xv = (j == 0) ? v.x : (j == 1) ? v.y : (j == 2) ? v.z : v.w;
      const float4* g4 = (const float4*)(g0 + j * NEXP);
      float4 a = g4[0], b = g4[1];
      p[0] += xv * a.x; p[1] += xv * a.y; p[2] += xv * a.z; p[3] += xv * a.w;
      p[4] += xv * b.x; p[5] += xv * b.y; p[6] += xv * b.z; p[7] += xv * b.w;
    }
  }
#pragma unroll
  for (int e = 0; e < NEXP; e++) {
#pragma unroll
    for (int off = 32; off > 0; off >>= 1) p[e] += __shfl_xor(p[e], off, 64);
  }
  if (lane == 0) {
    int i0 = 0;
    for (int e = 1; e < NEXP; e++) if (p[e] > p[i0]) i0 = e;
    int i1 = (i0 == 0) ? 1 : 0;
    for (int e = 0; e < NEXP; e++) if (e != i0 && p[e] > p[i1]) i1 = e;
    float l0 = p[i0], l1 = p[i1];
    float e1 = __expf(l1 - l0);
    float s = 1.f + e1;
    top_e[t * 2] = i0; top_e[t * 2 + 1] = i1;
    top_w[t * 2] = 1.f / s; top_w[t * 2 + 1] = e1 / s;
  }
}

// ---------------- fused count + offsets + scatter (single block, LDS atomics only) ----------------
__global__ void route_kernel(const int* __restrict__ top_e,
                             int* __restrict__ count,
                             int* __restrict__ offs,
                             int* __restrict__ tok_of,
                             int* __restrict__ slot_of) {
  __shared__ int hist[NEXP];
  __shared__ int cur[NEXP];
  int tid = threadIdx.x;  // 1024 threads, 4 entries each
  if (tid < NEXP) hist[tid] = 0;
  __syncthreads();
  int e[4];
#pragma unroll
  for (int j = 0; j < 4; j++) {
    int i = tid * 4 + j;
    e[j] = top_e[i];
    atomicAdd(&hist[e[j]], 1);
  }
  __syncthreads();
  if (tid == 0) {
    int o = 0;
    for (int k = 0; k < NEXP; k++) {
      offs[k] = o; cur[k] = o; count[k] = hist[k]; o += hist[k];
    }
  }
  __syncthreads();
#pragma unroll
  for (int j = 0; j < 4; j++) {
    int i = tid * 4 + j;
    int g = atomicAdd(&cur[e[j]], 1);
    tok_of[g] = i >> 1;
    slot_of[i] = g;
  }
}

// ---------------- GEMM1: act = silu(X w1^T) * (X w3^T), 128x64 tile ----------------
// Round-13 measured-best config (157 us). A (bf16 x): glds16, chunk-swizzle
// s = q ^ ((r>>1)&3). B (fp32 w1/w3): distance-2 register pipeline + counted
// vmcnt barrier (B loads cross the barrier with a full-step latency window).
#define G1_BM 128
#define G1_BF 64

__global__ __launch_bounds__(256, 3)
void gemm1_kernel(const unsigned short* __restrict__ xbf,
                  const float* __restrict__ w1,
                  const float* __restrict__ w3,
                  const int* __restrict__ count,
                  const int* __restrict__ offs,
                  const int* __restrict__ tok_of,
                  unsigned short* __restrict__ act) {
  int e = blockIdx.z;
  int cnt = count[e];
  int m0 = blockIdx.y * G1_BM;
  if (m0 >= cnt) return;
  int f0 = blockIdx.x * G1_BF;
  int off_e = offs[e];

  __shared__ __align__(16) unsigned short sA[2 * G1_BM * 32];   // 2 x 8 KB
  __shared__ __align__(16) unsigned short sB1[2 * G1_BF * 32];  // 2 x 4 KB
  __shared__ __align__(16) unsigned short sB3[2 * G1_BF * 32];  // 2 x 4 KB

  int tid = threadIdx.x;
  int lane = tid & 63, wv = tid >> 6;

  const unsigned short* ag[2];
  char* alb[2];
#pragma unroll
  for (int p = 0; p < 2; p++) {
    int c = tid + p * 256;
    int row = c >> 2, slot = c & 3;
    int gch = slot ^ ((row >> 1) & 3);
    int r = m0 + row;
    int tok = tok_of[off_e + (r < cnt ? r : 0)];
    ag[p] = xbf + (size_t)tok * HDIM + gch * 8;
    alb[p] = (char*)sA + (wv * 64 + p * 256) * 16;
  }
  const float *b1g, *b3g;
  unsigned short *b1l, *b3l;
  {
    int row = tid >> 2, slot = tid & 3;
    int gch = slot ^ ((row >> 1) & 3);
    size_t wrow = (size_t)e * FDIM + f0 + row;
    b1g = w1 + wrow * HDIM + gch * 8;
    b3g = w3 + wrow * HDIM + gch * 8;
    b1l = sB1 + tid * 8;
    b3l = sB3 + tid * 8;
  }

  int lrow = lane & 15, quad = lane >> 4;
  int wm = wv >> 1, wn = wv & 1;

  floatx4 acc1[4][2], acc3[4][2];
#pragma unroll
  for (int i = 0; i < 4; i++)
#pragma unroll
    for (int j = 0; j < 2; j++) {
      acc1[i][j] = (floatx4){0.f, 0.f, 0.f, 0.f};
      acc3[i][j] = (floatx4){0.f, 0.f, 0.f, 0.f};
    }

  const int NT = HDIM / BK;  // 32

  // prologue: stage tile 0 into buf 0 + preload B(1) into regs
#pragma unroll
  for (int p = 0; p < 2; p++) glds16(ag[p], alb[p]);
  asm volatile("" ::: "memory");   // glds stay older than the loads below
  {
    float4 a0 = *(const float4*)(b1g), a1 = *(const float4*)(b1g + 4);
    float4 c0 = *(const float4*)(b3g), c1 = *(const float4*)(b3g + 4);
    *(short8*)b1l = pack_bf16(a0, a1);
    *(short8*)b3l = pack_bf16(c0, c1);
  }
  float4 cu0 = *(const float4*)(b1g + BK), cu1 = *(const float4*)(b1g + BK + 4);
  float4 cv0 = *(const float4*)(b3g + BK), cv1 = *(const float4*)(b3g + BK + 4);
  PIPE_BARRIER();

  int cur = 0;
  for (int t = 0; t < NT; t++) {
    int nb = cur ^ 1;
    // B(t+1): regs aged one full step + barrier; compiler waits their vmcnt.
    *(short8*)(b1l + nb * (G1_BF * 32)) = pack_bf16(cu0, cu1);
    *(short8*)(b3l + nb * (G1_BF * 32)) = pack_bf16(cv0, cv1);
    // A(t+1) glds issued FIRST -> they are the ops vmcnt(4) waits for.
    int k1 = (t + 1 < NT) ? (t + 1) * BK : 0;
#pragma unroll
    for (int p = 0; p < 2; p++) glds16(ag[p] + k1, alb[p] + nb * 8192);
    asm volatile("" ::: "memory");
    // B(t+2) prefetch: stays in flight across the barrier.
    int k2 = (t + 2 < NT) ? (t + 2) * BK : 0;
    float4 nu0 = *(const float4*)(b1g + k2);
    float4 nu1 = *(const float4*)(b1g + k2 + 4);
    float4 nv0 = *(const float4*)(b3g + k2);
    float4 nv1 = *(const float4*)(b3g + k2 + 4);

    const unsigned short* sAc = sA + cur * (G1_BM * 32);
    const unsigned short* sB1c = sB1 + cur * (G1_BF * 32);
    const unsigned short* sB3c = sB3 + cur * (G1_BF * 32);

    short8 af[4], b1f[2], b3f[2];
#pragma unroll
    for (int ms = 0; ms < 4; ms++) {
      int r = wm * 64 + ms * 16 + lrow;
      int sl = quad ^ ((r >> 1) & 3);
      af[ms] = *(const short8*)(sAc + r * 32 + sl * 8);
    }
#pragma unroll
    for (int ns = 0; ns < 2; ns++) {
      int r = wn * 32 + ns * 16 + lrow;
      int sl = quad ^ ((r >> 1) & 3);
      b1f[ns] = *(const short8*)(sB1c + r * 32 + sl * 8);
      b3f[ns] = *(const short8*)(sB3c + r * 32 + sl * 8);
    }
#pragma unroll
    for (int ms = 0; ms < 4; ms++)
#pragma unroll
      for (int ns = 0; ns < 2; ns++) {
        acc1[ms][ns] = __builtin_amdgcn_mfma_f32_16x16x32_bf16(af[ms], b1f[ns], acc1[ms][ns], 0, 0, 0);
        acc3[ms][ns] = __builtin_amdgcn_mfma_f32_16x16x32_bf16(af[ms], b3f[ns], acc3[ms][ns], 0, 0, 0);
      }

    cu0 = nu0; cu1 = nu1; cv0 = nv0; cv1 = nv1;
    PIPE_BARRIER();
    cur = nb;
  }

#pragma unroll
  for (int ms = 0; ms < 4; ms++) {
#pragma unroll
    for (int reg = 0; reg < 4; reg++) {
      int slot = m0 + wm * 64 + ms * 16 + quad * 4 + reg;
      if (slot < cnt) {
        unsigned short* ar = act + (size_t)(off_e + slot) * FDIM + f0 + wn * 32;
#pragma unroll
        for (int ns = 0; ns < 2; ns++) {
          float h = acc1[ms][ns][reg];
          float g = acc3[ms][ns][reg];
          float a = h / (1.f + __expf(-h)) * g;
          ar[ns * 16 + lrow] = f2bf(a);
        }
      }
    }
  }
}

// ---------------- GEMM2: partial[sk] = act w2^T over K-slice, 128x128 tile ----------------
// SPLITK 2->4: active blocks ~512 -> ~1024+ (768 CU slots were ~30% idle).
// A (bf16 act): glds16. B (fp32 w2): distance-2 pipeline, counted-vmcnt barrier.
#define G2_BM 128
#define G2_BN 128
#define SPLITK 4
#define G2_KS (FDIM / SPLITK)   // 896

__global__ __launch_bounds__(256, 3)
void gemm2_kernel(const unsigned short* __restrict__ act,
                  const float* __restrict__ w2,
                  const int* __restrict__ count,
                  const int* __restrict__ offs,
                  float* __restrict__ part) {
  int zz = blockIdx.z;
  int e = zz & 7, sk = zz >> 3;
  int cnt = count[e];
  int m0 = blockIdx.y * G2_BM;
  if (m0 >= cnt) return;
  int h0 = blockIdx.x * G2_BN;
  int off_e = offs[e];
  int kb = sk * G2_KS;

  __shared__ __align__(16) unsigned short sA[2 * G2_BM * 32];  // 2 x 8 KB
  __shared__ __align__(16) unsigned short sB[2 * G2_BN * 32];  // 2 x 8 KB

  int tid = threadIdx.x;
  int lane = tid & 63, wv = tid >> 6;

  const unsigned short* ag[2];
  char* alb[2];
#pragma unroll
  for (int p = 0; p < 2; p++) {
    int c = tid + p * 256;
    int row = c >> 2, slot = c & 3;
    int gch = slot ^ ((row >> 1) & 3);
    int r = m0 + row;
    int rr = (r < cnt ? r : 0);
    ag[p] = act + (size_t)(off_e + rr) * FDIM + kb + gch * 8;
    alb[p] = (char*)sA + (wv * 64 + p * 256) * 16;
  }
  const float* bg[2];
  unsigned short* bl[2];
#pragma unroll
  for (int p = 0; p < 2; p++) {
    int c = tid + p * 256;
    int row = c >> 2, slot = c & 3;
    int gch = slot ^ ((row >> 1) & 3);
    bg[p] = w2 + ((size_t)e * HDIM + h0 + row) * FDIM + kb + gch * 8;
    bl[p] = sB + c * 8;
  }

  int lrow = lane & 15, quad = lane >> 4;
  int wm = wv >> 1, wn = wv & 1;

  floatx4 acc[4][4];
#pragma unroll
  for (int i = 0; i < 4; i++)
#pragma unroll
    for (int j = 0; j < 4; j++) acc[i][j] = (floatx4){0.f, 0.f, 0.f, 0.f};

  const int NT = G2_KS / BK;  // 28

  // prologue: stage tile 0 + preload B(1)
#pragma unroll
  for (int p = 0; p < 2; p++) glds16(ag[p], alb[p]);
  asm volatile("" ::: "memory");
#pragma unroll
  for (int p = 0; p < 2; p++) {
    float4 a0 = *(const float4*)(bg[p]);
    float4 a1 = *(const float4*)(bg[p] + 4);
    *(short8*)(bl[p]) = pack_bf16(a0, a1);
  }
  float4 cu0[2], cu1[2];
#pragma unroll
  for (int p = 0; p < 2; p++) {
    cu0[p] = *(const float4*)(bg[p] + BK);
    cu1[p] = *(const float4*)(bg[p] + BK + 4);
  }
  PIPE_BARRIER();

  int cur = 0;
  for (int t = 0; t < NT; t++) {
    int nb = cur ^ 1;
#pragma unroll
    for (int p = 0; p < 2; p++)
      *(short8*)(bl[p] + nb * (G2_BN * 32)) = pack_bf16(cu0[p], cu1[p]);
    int k1 = (t + 1 < NT) ? (t + 1) * BK : 0;
#pragma unroll
    for (int p = 0; p < 2; p++) glds16(ag[p] + k1, alb[p] + nb * 8192);
    asm volatile("" ::: "memory");
    int k2 = (t + 2 < NT) ? (t + 2) * BK : 0;
    float4 nu0[2], nu1[2];
#pragma unroll
    for (int p = 0; p < 2; p++) {
      nu0[p] = *(const float4*)(bg[p] + k2);
      nu1[p] = *(const float4*)(bg[p] + k2 + 4);
    }

    const unsigned short* sAc = sA + cur * (G2_BM * 32);
    const unsigned short* sBc = sB + cur * (G2_BN * 32);

    short8 af[4], bf[4];
#pragma unroll
    for (int ms = 0; ms < 4; ms++) {
      int r = wm * 64 + ms * 16 + lrow;
      int sl = quad ^ ((r >> 1) & 3);
      af[ms] = *(const short8*)(sAc + r * 32 + sl * 8);
    }
#pragma unroll
    for (int ns = 0; ns < 4; ns++) {
      int r = wn * 64 + ns * 16 + lrow;
      int sl = quad ^ ((r >> 1) & 3);
      bf[ns] = *(const short8*)(sBc + r * 32 + sl * 8);
    }
#pragma unroll
    for (int ms = 0; ms < 4; ms++)
#pragma unroll
      for (int ns = 0; ns < 4; ns++)
        acc[ms][ns] = __builtin_amdgcn_mfma_f32_16x16x32_bf16(af[ms], bf[ns], acc[ms][ns], 0, 0, 0);

#pragma unroll
    for (int p = 0; p < 2; p++) { cu0[p] = nu0[p]; cu1[p] = nu1[p]; }
    PIPE_BARRIER();
    cur = nb;
  }

#pragma unroll
  for (int ms = 0; ms < 4; ms++) {
#pragma unroll
    for (int reg = 0; reg < 4; reg++) {
      int slot = m0 + wm * 64 + ms * 16 + quad * 4 + reg;
      if (slot < cnt) {
        float* crow = part + ((size_t)sk * 4096 + off_e + slot) * HDIM + h0 + wn * 64;
#pragma unroll
        for (int ns = 0; ns < 4; ns++)
          crow[ns * 16 + lrow] = acc[ms][ns][reg];
      }
    }
  }
}

// ---------------- combine: out[t] = sum_k w_k * sum_sk part[sk][g_k] ----------------
__global__ void combine_kernel(const float* __restrict__ part,
                               const int* __restrict__ slot_of,
                               const float* __restrict__ top_w,
                               float* __restrict__ out) {
  int t = blockIdx.x;
  int g0 = slot_of[t * 2], g1 = slot_of[t * 2 + 1];
  float w0 = top_w[t * 2], w1 = top_w[t * 2 + 1];
  int i = threadIdx.x;   // 256 threads x float4 = 1024 floats
  float4 s0 = {0.f, 0.f, 0.f, 0.f}, s1 = {0.f, 0.f, 0.f, 0.f};
#pragma unroll
  for (int sk = 0; sk < SPLITK; sk++) {
    float4 a = ((const float4*)(part + ((size_t)sk * 4096 + g0) * HDIM))[i];
    float4 b = ((const float4*)(part + ((size_t)sk * 4096 + g1) * HDIM))[i];
    s0.x += a.x; s0.y += a.y; s0.z += a.z; s0.w += a.w;
    s1.x += b.x; s1.y += b.y; s1.z += b.z; s1.w += b.w;
  }
  float4 r;
  r.x = w0 * s0.x + w1 * s1.x;
  r.y = w0 * s0.y + w1 * s1.y;
  r.z = w0 * s0.z + w1 * s1.z;
  r.w = w0 * s0.w + w1 * s1.w;
  ((float4*)(out + (size_t)t * HDIM))[i] = r;
}

// ---------------- launcher ----------------
extern "C" void kernel_launch(void* const* d_in, const int* in_sizes, int n_in,
                              void* d_out, int out_size, void* d_ws, size_t ws_size,
                              hipStream_t stream) {
  const float* x  = (const float*)d_in[0];
  const float* gw = (const float*)d_in[1];
  const float* w1 = (const float*)d_in[2];
  const float* w3 = (const float*)d_in[3];
  const float* w2 = (const float*)d_in[4];
  float* out = (float*)d_out;

  char* ws = (char*)d_ws;
  const size_t MB = 1ull << 20;
  // layout (~99 MB total):
  //   [0,1)    small buffers
  //   [1,5)    xbf (4 MB)
  //   [5,35)   act  (28 MB used)
  //   [35,99)  part (64 MB, SPLITK=4)
  float* top_w = (float*)(ws);
  int* top_e   = (int*)(ws + 16384);
  int* slot_of = (int*)(ws + 32768);
  int* tok_of  = (int*)(ws + 49152);
  int* count   = (int*)(ws + 65536);
  int* offs    = (int*)(ws + 65536 + 64);

  unsigned short* xbf = (unsigned short*)(ws + 1 * MB);
  unsigned short* act = (unsigned short*)(ws + 5 * MB);
  float* part = (float*)(ws + 35 * MB);

  gate_kernel<<<TOKENS / 4, 256, 0, stream>>>(x, gw, xbf, top_e, top_w);
  route_kernel<<<1, 1024, 0, stream>>>(top_e, count, offs, tok_of, slot_of);
  gemm1_kernel<<<dim3(FDIM / G1_BF, TOKENS / G1_BM, NEXP), 256, 0, stream>>>(
      xbf, w1, w3, count, offs, tok_of, act);
  gemm2_kernel<<<dim3(HDIM / G2_BN, TOKENS / G2_BM, NEXP * SPLITK), 256, 0, stream>>>(
      act, w2, count, offs, part);
  combine_kernel<<<TOKENS, 256, 0, stream>>>(part, slot_of, top_w, out);
}